// Round 9
// baseline (163.187 us; speedup 1.0000x reference)
//
#include <hip/hip_runtime.h>
#include <hip/hip_bf16.h>

// S=64, C=27. DOTLEN = 8640 = 2160 float4/row; state=320; comb=640; hidden=64.
// Restructure: ns1 never materialized.
//   agg0 = agg_W0@(states1+b2) [y0] + M@h1,  M[i][n*64+k] = sum_j W0[i][n*320+j]*W2[n][j][k]
//   h1 = relu(hA + W1b@agg1),  hA = b1 + W1a@states1
// K1 dispatch = 1080 gemv blocks + 27 hA blocks + 270 M/y0 blocks (independent work
// hidden under the bandwidth-bound gemv). Then K2 -> K3 -> K4, all small+parallel.

#define NG 1080           // gemv blocks (27 nodes x 40 x 8 rows)
#define NA 27             // hA blocks
#define NM 270            // M blocks (27 nodes x 10 x 32 rows)

__device__ __forceinline__ float wave_reduce_sum(float v) {
    v += __shfl_xor(v, 32, 64);
    v += __shfl_xor(v, 16, 64);
    v += __shfl_xor(v, 8, 64);
    v += __shfl_xor(v, 4, 64);
    v += __shfl_xor(v, 2, 64);
    v += __shfl_xor(v, 1, 64);
    return v;
}

__device__ __forceinline__ float fma4s(float4 w, float4 x, float acc) {
    acc = fmaf(w.x, x.x, acc);
    acc = fmaf(w.y, x.y, acc);
    acc = fmaf(w.z, x.z, acc);
    acc = fmaf(w.w, x.w, acc);
    return acc;
}

__device__ __forceinline__ float4 add4(float4 a, float4 b) {
    return make_float4(a.x + b.x, a.y + b.y, a.z + b.z, a.w + b.w);
}

// ---------------------------------------------------------------------------
// K1: unified dispatch.
__global__ void __launch_bounds__(256) K1(
    const float* __restrict__ aggW1,    // [8640][8640] block rows
    const float* __restrict__ x2,       // states2 [27][8640]
    const float* __restrict__ aggb1,    // [8640]
    const float* __restrict__ states1,  // [27][320]
    const float* __restrict__ W1,       // up_W1_1 [27][64][640]
    const float* __restrict__ b1,       // [27][64]
    const float* __restrict__ W2,       // up_W2_1 [27][320][64]
    const float* __restrict__ b2,       // up_b2_1 [27][320] (flat 8640)
    const float* __restrict__ aggW0,    // [320][8640]
    float* __restrict__ agg1,           // ws [8640]
    float* __restrict__ hA,             // ws [1728]
    float* __restrict__ y0p,            // ws [27][320]
    float* __restrict__ M)              // ws [320][1728]
{
    __shared__ __align__(16) float sh[640];
    const int b   = blockIdx.x;
    const int tid = threadIdx.x;
    const int wv  = tid >> 6, lane = tid & 63;

    if (b < NG) {
        // ---- gemv: agg1 rows (exact R5 structure) ----
        const int node = b / 40;
        const int row0 = node * 320 + (b % 40) * 8;
        const float4* __restrict__ xf = reinterpret_cast<const float4*>(x2) + (size_t)node * 2160;
        const float4* wp[8];
        #pragma unroll
        for (int r = 0; r < 8; ++r)
            wp[r] = reinterpret_cast<const float4*>(aggW1) + (size_t)(row0 + r) * 2160;

        float4 acc[8];
        #pragma unroll
        for (int r = 0; r < 8; ++r) acc[r] = make_float4(0.f, 0.f, 0.f, 0.f);

        for (int j = tid; j < 2160; j += 256) {
            float4 xv = xf[j];
            #pragma unroll
            for (int r = 0; r < 8; ++r) {
                float4 w = wp[r][j];
                acc[r].x = fmaf(w.x, xv.x, acc[r].x);
                acc[r].y = fmaf(w.y, xv.y, acc[r].y);
                acc[r].z = fmaf(w.z, xv.z, acc[r].z);
                acc[r].w = fmaf(w.w, xv.w, acc[r].w);
            }
        }
        float s[8];
        #pragma unroll
        for (int r = 0; r < 8; ++r) {
            s[r] = (acc[r].x + acc[r].y) + (acc[r].z + acc[r].w);
            s[r] = wave_reduce_sum(s[r]);
        }
        if (lane == 0) {
            #pragma unroll
            for (int r = 0; r < 8; ++r) sh[wv * 8 + r] = s[r];
        }
        __syncthreads();
        if (tid < 8) {
            float v = sh[tid] + sh[8 + tid] + sh[16 + tid] + sh[24 + tid];
            agg1[row0 + tid] = v + aggb1[row0 + tid];
        }
    } else if (b < NG + NA) {
        // ---- hA[n][k] = b1 + W1[:, 0:320] @ states1[n] ----
        const int n = b - NG;
        float4* shf = reinterpret_cast<float4*>(sh);
        const float4* __restrict__ s1f = reinterpret_cast<const float4*>(states1) + (size_t)n * 80;
        if (tid < 80) shf[tid] = s1f[tid];
        __syncthreads();
        for (int kk = 0; kk < 16; ++kk) {
            const int k = wv * 16 + kk;
            const float4* __restrict__ Wf = reinterpret_cast<const float4*>(W1) + ((size_t)n * 64 + k) * 160;
            float acc = 0.f;
            for (int j = lane; j < 80; j += 64)
                acc = fma4s(Wf[j], shf[j], acc);
            acc = wave_reduce_sum(acc);
            if (lane == 0) hA[n * 64 + k] = acc + b1[n * 64 + k];
        }
    } else {
        // ---- M + y0 partials: node n, rows i0..i0+31 ----
        const int t  = b - NG - NA;
        const int n  = t / 10;
        const int i0 = (t % 10) * 32;
        // stage xs[j] = states1[n][j] + b2[n][j]
        float4* shf = reinterpret_cast<float4*>(sh);
        const float4* __restrict__ s1f = reinterpret_cast<const float4*>(states1) + (size_t)n * 80;
        const float4* __restrict__ b2f = reinterpret_cast<const float4*>(b2) + (size_t)n * 80;
        if (tid < 80) shf[tid] = add4(s1f[tid], b2f[tid]);
        __syncthreads();

        const int r0 = i0 + wv * 8;     // this wave's 8 rows (absolute 0..319)
        const float* __restrict__ W2n = W2 + (size_t)n * 320 * 64;
        float accm[8];
        #pragma unroll
        for (int rr = 0; rr < 8; ++rr) accm[rr] = 0.f;

        #pragma unroll 2
        for (int j = 0; j < 320; ++j) {
            float w2 = W2n[(size_t)j * 64 + lane];          // coalesced across lanes
            #pragma unroll
            for (int rr = 0; rr < 8; ++rr) {
                float w0 = aggW0[(size_t)(r0 + rr) * 8640 + n * 320 + j];  // uniform
                accm[rr] = fmaf(w0, w2, accm[rr]);
            }
        }
        #pragma unroll
        for (int rr = 0; rr < 8; ++rr)
            M[(size_t)(r0 + rr) * 1728 + n * 64 + lane] = accm[rr];

        // y0 partial for the same rows (W0 slice is L1-hot)
        #pragma unroll
        for (int rr = 0; rr < 8; ++rr) {
            const int r = r0 + rr;
            float yv = 0.f;
            #pragma unroll
            for (int m = 0; m < 5; ++m) {
                int j = lane + 64 * m;
                yv = fmaf(aggW0[(size_t)r * 8640 + n * 320 + j], sh[j], yv);
            }
            yv = wave_reduce_sum(yv);
            if (lane == 0) y0p[n * 320 + r] = yv;
        }
    }
}

// ---------------------------------------------------------------------------
// K2: h1[n][k] = relu(hA[n][k] + W1[:,320:640] @ agg1[n]). 432 blocks.
__global__ void __launch_bounds__(256) K2(
    const float* __restrict__ agg1,  // ws [8640]
    const float* __restrict__ W1,    // [27][64][640]
    const float* __restrict__ hA,    // ws [1728]
    float*       __restrict__ h1)    // ws [1728]
{
    __shared__ __align__(16) float sh[320];
    const int nb  = blockIdx.x;
    const int n   = nb / 16;
    const int tid = threadIdx.x;
    const int wv  = tid >> 6, lane = tid & 63;

    float4* shf = reinterpret_cast<float4*>(sh);
    const float4* __restrict__ a1f = reinterpret_cast<const float4*>(agg1) + (size_t)n * 80;
    if (tid < 80) shf[tid] = a1f[tid];
    __syncthreads();

    const int k = (nb % 16) * 4 + wv;
    const float4* __restrict__ Wf = reinterpret_cast<const float4*>(W1) + ((size_t)n * 64 + k) * 160 + 80;
    float acc = 0.f;
    for (int j = lane; j < 80; j += 64)
        acc = fma4s(Wf[j], shf[j], acc);
    acc = wave_reduce_sum(acc);
    if (lane == 0) h1[n * 64 + k] = fmaxf(hA[n * 64 + k] + acc, 0.f);
}

// ---------------------------------------------------------------------------
// K3: agg0[i] = sum_n y0p[n][i] + agg_b0[i] + M[i,:] @ h1. 80 blocks x 4 rows.
__global__ void __launch_bounds__(256) K3(
    const float* __restrict__ M,      // ws [320][1728]
    const float* __restrict__ h1,     // ws [1728]
    const float* __restrict__ y0p,    // ws [27][320]
    const float* __restrict__ aggb0,  // [320]
    float*       __restrict__ agg0)   // ws [320]
{
    __shared__ __align__(16) float hs[1728];
    const int tid = threadIdx.x;
    const int wv  = tid >> 6, lane = tid & 63;

    float4* hsf = reinterpret_cast<float4*>(hs);
    const float4* __restrict__ h1f = reinterpret_cast<const float4*>(h1);
    for (int j = tid; j < 432; j += 256) hsf[j] = h1f[j];
    __syncthreads();

    const int i = blockIdx.x * 4 + wv;   // 0..319
    const float4* __restrict__ Mf = reinterpret_cast<const float4*>(M) + (size_t)i * 432;
    float acc = 0.f;
    for (int j = lane; j < 432; j += 64)
        acc = fma4s(Mf[j], hsf[j], acc);
    if (lane < 27) acc += y0p[lane * 320 + i];
    acc = wave_reduce_sum(acc);
    if (lane == 0) agg0[i] = acc + aggb0[i];
}

// ---------------------------------------------------------------------------
// K4: root MLP, 80 blocks; each block recomputes h0 (L2-hot weights), then 4 out rows.
__global__ void __launch_bounds__(256) K4(
    const float* __restrict__ state0,  // [320]
    const float* __restrict__ ext,     // [320]
    const float* __restrict__ agg0,    // ws [320]
    const float* __restrict__ W1,      // up_W1_0 [64][640]
    const float* __restrict__ b1,      // [64]
    const float* __restrict__ W2,      // up_W2_0 [320][64]
    const float* __restrict__ b2,      // [320]
    float*       __restrict__ out)     // [320]
{
    __shared__ __align__(16) float comb[640];
    __shared__ float h[64];
    const int tid = threadIdx.x;
    const int wv  = tid >> 6, lane = tid & 63;

    float4* combf = reinterpret_cast<float4*>(comb);
    const float4* __restrict__ s0f = reinterpret_cast<const float4*>(state0);
    const float4* __restrict__ exf = reinterpret_cast<const float4*>(ext);
    const float4* __restrict__ agf = reinterpret_cast<const float4*>(agg0);
    if (tid < 80)       combf[tid] = add4(s0f[tid], exf[tid]);
    else if (tid < 160) combf[tid] = agf[tid - 80];
    __syncthreads();

    const float4* __restrict__ cf = reinterpret_cast<const float4*>(comb);
    for (int kk = 0; kk < 16; ++kk) {
        const int k = wv * 16 + kk;
        const float4* __restrict__ Wf = reinterpret_cast<const float4*>(W1) + (size_t)k * 160;
        float acc = 0.f;
        for (int j = lane; j < 160; j += 64)
            acc = fma4s(Wf[j], cf[j], acc);
        acc = wave_reduce_sum(acc);
        if (lane == 0) h[k] = fmaxf(acc + b1[k], 0.f);
    }
    __syncthreads();

    const int i = blockIdx.x * 4 + wv;   // 0..319
    float acc = W2[(size_t)i * 64 + lane] * h[lane];
    acc = wave_reduce_sum(acc);
    if (lane == 0) out[i] = comb[i] + acc + b2[i];
}

extern "C" void kernel_launch(void* const* d_in, const int* in_sizes, int n_in,
                              void* d_out, int out_size, void* d_ws, size_t ws_size,
                              hipStream_t stream) {
    const float* ext      = (const float*)d_in[0];
    const float* state0   = (const float*)d_in[1];
    const float* states1  = (const float*)d_in[2];
    const float* states2  = (const float*)d_in[3];
    const float* agg_W0   = (const float*)d_in[4];
    const float* agg_b0   = (const float*)d_in[5];
    const float* agg_W1   = (const float*)d_in[6];
    const float* agg_b1   = (const float*)d_in[7];
    const float* up_W1_0  = (const float*)d_in[8];
    const float* up_b1_0  = (const float*)d_in[9];
    const float* up_W2_0  = (const float*)d_in[10];
    const float* up_b2_0  = (const float*)d_in[11];
    const float* up_W1_1  = (const float*)d_in[12];
    const float* up_b1_1  = (const float*)d_in[13];
    const float* up_W2_1  = (const float*)d_in[14];
    const float* up_b2_1  = (const float*)d_in[15];

    float* out  = (float*)d_out;
    float* ws   = (float*)d_ws;
    float* agg1 = ws;              // 8640
    float* hA   = ws + 8640;       // 1728
    float* h1   = ws + 10368;      // 1728
    float* y0p  = ws + 12096;      // 8640
    float* agg0 = ws + 20736;      // 320
    float* M    = ws + 21056;      // 552960 (2.2 MB)

    K1<<<NG + NA + NM, 256, 0, stream>>>(agg_W1, states2, agg_b1, states1,
                                         up_W1_1, up_b1_1, up_W2_1, up_b2_1,
                                         agg_W0, agg1, hA, y0p, M);
    K2<<<432, 256, 0, stream>>>(agg1, up_W1_1, hA, h1);
    K3<<<80,  256, 0, stream>>>(M, h1, y0p, agg_b0, agg0);
    K4<<<80,  256, 0, stream>>>(state0, ext, agg0, up_W1_0, up_b1_0, up_W2_0, up_b2_0, out);
}